// Round 14
// baseline (79.016 us; speedup 1.0000x reference)
//
#include <hip/hip_runtime.h>
#include <math.h>

typedef __attribute__((ext_vector_type(8))) short short8;
typedef __attribute__((ext_vector_type(8))) _Float16 half8;
typedef __attribute__((ext_vector_type(4))) float f32x4;

#define NSP 4096
#define CIN 256
#define ICH 128
#define SPLITS 4
#define TPS 16
#define LOG2E 1.44269504088896f

__device__ __forceinline__ unsigned short f2h(float x){
  union { _Float16 h; unsigned short u; } v; v.h = (_Float16)x; return v.u;
}
__device__ __forceinline__ float h2f(unsigned short u){
  union { _Float16 h; unsigned short u; } v; v.u = u; return (float)v.h;
}
__device__ __forceinline__ unsigned pk2h(float a, float b){
  union { __fp16 __attribute__((ext_vector_type(2))) v; unsigned u; } r;
  r.v = __builtin_amdgcn_cvt_pkrtz(a, b);
  return r.u;
}
// raw 2^x via v_exp_f32 (no OCML denormal fixup)
__device__ __forceinline__ float fexp2(float x){
  float r;
  asm("v_exp_f32 %0, %1" : "=v"(r) : "v"(x));
  return r;
}
// LDS anti-bank-conflict swizzle (element units; 8-chunk preserving)
__device__ __forceinline__ int swz(int row, int e){ return e ^ ((row & 7) << 3); }

__device__ __forceinline__ f32x4 mfmah(short8 a, short8 b, f32x4 c){
  union { short8 s; half8 h; } ua, ub; ua.s = a; ub.s = b;
  return __builtin_amdgcn_mfma_f32_16x16x32_f16(ua.h, ub.h, c, 0, 0, 0);
}

__device__ __forceinline__ void st4h(unsigned short* p, unsigned short a, unsigned short b,
                                     unsigned short c, unsigned short d){
  ushort4 v; v.x=a; v.y=b; v.z=c; v.w=d;
  *(ushort4*)p = v;
}

// async global->LDS, 16B per lane. LDS dest = wave-uniform base + lane*16 (linear).
__device__ __forceinline__ void gload_lds16(const unsigned short* g, unsigned short* l){
  __builtin_amdgcn_global_load_lds(
      (const __attribute__((address_space(1))) unsigned int*)g,
      (__attribute__((address_space(3))) unsigned int*)l, 16, 0, 0);
}

// Stage a 64x128 fp16 tile into LDS flat [64][128] with read-side XOR swizzle
// pre-applied on the SOURCE address (rule 21).
__device__ __forceinline__ void stage_nc(const unsigned short* gbase, unsigned short* lds,
                                         int w, int l){
  #pragma unroll
  for (int i=0;i<4;++i){
    int rl = 16*w + 4*i + (l>>4);
    int eg = ((l&15)*8) ^ ((rl&7)<<3);
    gload_lds16(gbase + (size_t)rl*128 + eg, lds + w*2048 + i*512);
  }
}

// k-order permutation for PV (within each 32-block of m):
// store position p for true m: p = ((m>>4)&1)<<2 | ((m>>2)&3)<<3 | (m&3)
__device__ __forceinline__ int kperm(int q){
  return ((q>>4)&1)*4 + ((q>>2)&3)*8 + (q&3);
}

// ---------------------------------------------------------------------------
// Fused 3-branch conv+BN+ReLU (unchanged from R13)
// ---------------------------------------------------------------------------
__global__ __launch_bounds__(256) void conv_fused_k(
    const float* __restrict__ x,
    const float* __restrict__ w0, const float* __restrict__ b0,
    const float* __restrict__ ga0, const float* __restrict__ be0,
    const float* __restrict__ me0, const float* __restrict__ va0,
    const float* __restrict__ w1, const float* __restrict__ b1,
    const float* __restrict__ ga1, const float* __restrict__ be1,
    const float* __restrict__ me1, const float* __restrict__ va1,
    const float* __restrict__ w2, const float* __restrict__ b2,
    const float* __restrict__ ga2, const float* __restrict__ be2,
    const float* __restrict__ me2, const float* __restrict__ va2,
    unsigned short* __restrict__ outg, unsigned short* __restrict__ outt,
    unsigned short* __restrict__ outp)
{
  const int b = blockIdx.z, nt = blockIdx.x, ot = blockIdx.y;
  const int n0 = nt*64, o0 = ot*64;
  const int t = threadIdx.x, w = t>>6, l = t&63;
  __shared__ unsigned short xs[64][64];
  __shared__ unsigned short ws[3][64][64];
  __shared__ float sc_s[3][64], sh_s[3][64];
  if (t < 64){
    int o = o0 + t;
    float s0 = ga0[o]*rsqrtf(va0[o]+1e-5f);
    sc_s[0][t]=s0; sh_s[0][t]=be0[o]-me0[o]*s0+b0[o]*s0;
    float s1 = ga1[o]*rsqrtf(va1[o]+1e-5f);
    sc_s[1][t]=s1*LOG2E; sh_s[1][t]=(be1[o]-me1[o]*s1+b1[o]*s1)*LOG2E;
    float s2 = ga2[o]*rsqrtf(va2[o]+1e-5f);
    sc_s[2][t]=s2; sh_s[2][t]=be2[o]-me2[o]*s2+b2[o]*s2;
  }
  const f32x4 Z = {0.f,0.f,0.f,0.f};
  f32x4 acc[3][4];
  #pragma unroll
  for (int br=0;br<3;++br) for (int i=0;i<4;++i) acc[br][i] = Z;
  const float* Wt[3] = {w0, w1, w2};

  for (int kc = 0; kc < CIN; kc += 64){
    __syncthreads();
    #pragma unroll
    for (int p = 0; p < 4; ++p){
      int cw = p*16 + (t>>4);
      int q4 = (t&15)*4;
      float4 xv = *(const float4*)(x + ((size_t)b*CIN + kc + cw)*NSP + n0 + q4);
      float xa[4] = {xv.x, xv.y, xv.z, xv.w};
      #pragma unroll
      for (int i=0;i<4;++i){
        int r = q4 + i;
        xs[r][swz(r, cw)] = f2h(xa[i]);
      }
      #pragma unroll
      for (int br=0;br<3;++br){
        float4 wv = *(const float4*)(Wt[br] + (size_t)(o0 + cw)*CIN + kc + q4);
        int cs = swz(cw, q4);
        st4h(&ws[br][cw][cs], f2h(wv.x), f2h(wv.y), f2h(wv.z), f2h(wv.w));
      }
    }
    __syncthreads();
    #pragma unroll
    for (int kf = 0; kf < 2; ++kf){
      int ko = kf*32 + (l>>4)*8;
      int wr = 16*w + (l&15);
      short8 wf0 = *(const short8*)&ws[0][wr][swz(wr, ko)];
      short8 wf1 = *(const short8*)&ws[1][wr][swz(wr, ko)];
      short8 wf2 = *(const short8*)&ws[2][wr][swz(wr, ko)];
      #pragma unroll
      for (int nf = 0; nf < 4; ++nf){
        int xr = 16*nf + (l&15);
        short8 xf = *(const short8*)&xs[xr][swz(xr, ko)];
        acc[0][nf] = mfmah(wf0, xf, acc[0][nf]);
        acc[1][nf] = mfmah(xf, wf1, acc[1][nf]);
        acc[2][nf] = mfmah(xf, wf2, acc[2][nf]);
      }
    }
  }
  #pragma unroll
  for (int j=0;j<4;++j){
    int ol = 16*w + (l>>4)*4 + j;
    float s = sc_s[0][ol], sh = sh_s[0][ol];
    #pragma unroll
    for (int nf=0;nf<4;++nf){
      int n = n0 + 16*nf + (l&15);
      int nst = (n & ~31) | kperm(n & 31);
      float v = fmaxf(acc[0][nf][j]*s + sh, 0.f);
      outg[((size_t)b*ICH + o0 + ol)*NSP + nst] = f2h(v);
    }
  }
  {
    int ol = 16*w + (l&15);
    float s1 = sc_s[1][ol], sh1 = sh_s[1][ol];
    float s2 = sc_s[2][ol], sh2 = sh_s[2][ol];
    #pragma unroll
    for (int nf=0; nf<4; ++nf)
      #pragma unroll
      for (int j=0;j<4;++j){
        int n = n0 + 16*nf + (l>>4)*4 + j;
        float v1 = fmaxf(acc[1][nf][j]*s1 + sh1, 0.f);
        float v2 = fmaxf(acc[2][nf][j]*s2 + sh2, 0.f);
        outt[((size_t)b*NSP + n)*ICH + o0 + ol] = f2h(v1);
        outp[((size_t)b*NSP + n)*ICH + o0 + ol] = f2h(v2);
      }
  }
}

// ---------------------------------------------------------------------------
// Flash attention, software-pipelined: QK[it+1] (MFMA) and softmax[it] (VALU)
// share one barrier region with no data dependence -> per-wave pipe overlap.
// K prefetch distance 2, V distance 1, counted vmcnt(8/4/0). fa/fb score
// ping-pong via 2x-unrolled loop (all reg indices static). 256 thr, Q=128,
// SPLITS=4, grid 512 = 2 blocks/CU (64 KB LDS).
// ---------------------------------------------------------------------------
__global__ __launch_bounds__(256, 2) void attn_k(
  const unsigned short* __restrict__ thp, const unsigned short* __restrict__ php,
  const unsigned short* __restrict__ gb, unsigned short* __restrict__ ypart,
  float* __restrict__ ml)
{
  const int bx = blockIdx.x;
  const int xcd = bx & 7, jj = bx >> 3;
  const int combo = xcd*2 + (jj>>5);
  const int qt = jj & 31;
  const int b = combo & 3, s = combo >> 2;
  const int n0 = qt*128;
  const int t = threadIdx.x, w = t>>6, l = t&63;

  __shared__ unsigned short kbuf[2][8192];
  __shared__ unsigned short vbuf[2][8192];
  unsigned short* kb0 = kbuf[0];
  unsigned short* kb1 = kbuf[1];
  unsigned short* vb0 = vbuf[0];
  unsigned short* vb1 = vbuf[1];

  // ---- stage Q halves through kb0/kb1, pull fragments ----
  stage_nc(thp + ((size_t)b*NSP + n0      )*ICH, kb0, w, l);
  stage_nc(thp + ((size_t)b*NSP + n0 + 64 )*ICH, kb1, w, l);
  __syncthreads();
  short8 qf0[4], qf1[4];
  {
    int qr = 16*w + (l&15);
    #pragma unroll
    for (int kf=0;kf<4;++kf){
      int ko = kf*32 + (l>>4)*8;
      qf0[kf] = *(const short8*)&kb0[qr*128 + swz(qr, ko)];
      qf1[kf] = *(const short8*)&kb1[qr*128 + swz(qr, ko)];
    }
  }
  __syncthreads();

  const f32x4 Z = {0.f,0.f,0.f,0.f};
  f32x4 oa0[8], oa1[8];
  #pragma unroll
  for (int i=0;i<8;++i){ oa0[i]=Z; oa1[i]=Z; }
  float m0r = -1e30f, m1r = -1e30f;
  float l0r = 0.f, l1r = 0.f;
  unsigned pk0[8], pk1[8];
  f32x4 fa0[4], fa1[4], fb0[4], fb1[4];

  const int tile0 = s*TPS;

  // ---- hoisted per-lane staging pointers ----
  const unsigned short* kp[4];
  const unsigned short* vp[4];
  {
    const unsigned short* kbase = php + ((size_t)b*NSP + tile0*64)*ICH;
    const unsigned short* vbase = gb + (size_t)b*ICH*NSP + tile0*64;
    #pragma unroll
    for (int i=0;i<4;++i){
      int rl = 16*w + 4*i + (l>>4);
      int eg = ((l&15)*8) ^ ((rl&7)<<3);
      kp[i] = kbase + (size_t)rl*128 + eg;
      int cl = 32*w + 8*i + (l>>3);
      int me = ((l&7)*8) ^ ((cl&7)<<3);
      vp[i] = vbase + (size_t)cl*NSP + me;
    }
  }
  // prologue: issue K0->kb0, V0->vb0, K1->kb1
  {
    unsigned short* kd = kb0 + w*2048;
    unsigned short* vd = vb0 + w*2048;
    #pragma unroll
    for (int i=0;i<4;++i){ gload_lds16(kp[i], kd + i*512); kp[i] += 64*ICH; }
    #pragma unroll
    for (int i=0;i<4;++i){ gload_lds16(vp[i], vd + i*512); vp[i] += 64; }
    unsigned short* kd1 = kb1 + w*2048;
    #pragma unroll
    for (int i=0;i<4;++i){ gload_lds16(kp[i], kd1 + i*512); kp[i] += 64*ICH; }
  }
  asm volatile("s_waitcnt vmcnt(4)" ::: "memory");  // K0,V0 ready (K1 in flight)
  __builtin_amdgcn_s_barrier();
  __builtin_amdgcn_sched_barrier(0);
  // QK[0] from kb0 -> fa
  #pragma unroll
  for (int i=0;i<4;++i){ fa0[i]=Z; fa1[i]=Z; }
  #pragma unroll
  for (int mf=0; mf<4; ++mf){
    int kr = 16*mf + (l&15);
    #pragma unroll
    for (int kf=0; kf<4; ++kf){
      short8 bh = *(const short8*)&kb0[kr*128 + swz(kr, kf*32 + (l>>4)*8)];
      fa0[mf] = mfmah(bh, qf0[kf], fa0[mf]);
      fa1[mf] = mfmah(bh, qf1[kf], fa1[mf]);
    }
  }
  __builtin_amdgcn_s_barrier();   // all QK[0] reads of kb0 done before K2 writes

  // iteration body: curc = it&1 (compile-time per call site).
  // c0/c1 = scores S[it]; n0/n1 receive S[it+1].
  auto iter_body = [&](int it, int curc, f32x4* c0, f32x4* c1, f32x4* n0, f32x4* n1){
    unsigned short* kcur_n = curc ? kb0 : kb1;   // holds K[it+1]
    unsigned short* vcur   = curc ? vb1 : vb0;   // holds V[it]
    unsigned short* kfree  = curc ? kb1 : kb0;   // K[it] slot (free) <- K[it+2]
    unsigned short* vfree  = curc ? vb0 : vb1;   // V[it-1] slot (free) <- V[it+1]

    // (1) issue prefetches
    if (it <= TPS-3){
      unsigned short* kd = kfree + w*2048;
      #pragma unroll
      for (int i=0;i<4;++i){ gload_lds16(kp[i], kd + i*512); kp[i] += 64*ICH; }
    }
    if (it <= TPS-2){
      unsigned short* vd = vfree + w*2048;
      #pragma unroll
      for (int i=0;i<4;++i){ gload_lds16(vp[i], vd + i*512); vp[i] += 64; }
    }
    // (2) wait K[it+1], V[it] arrived (keep just-issued in flight)
    if (it <= TPS-3)      asm volatile("s_waitcnt vmcnt(8)" ::: "memory");
    else if (it == TPS-2) asm volatile("s_waitcnt vmcnt(4)" ::: "memory");
    else                  asm volatile("s_waitcnt vmcnt(0)" ::: "memory");
    __builtin_amdgcn_s_barrier();
    __builtin_amdgcn_sched_barrier(0);

    // (3) QK[it+1] (MFMA) || softmax[it] (VALU) — independent, co-scheduled
    if (it <= TPS-2){
      #pragma unroll
      for (int i=0;i<4;++i){ n0[i]=Z; n1[i]=Z; }
      #pragma unroll
      for (int mf=0; mf<4; ++mf){
        int kr = 16*mf + (l&15);
        #pragma unroll
        for (int kf=0; kf<4; ++kf){
          short8 bh = *(const short8*)&kcur_n[kr*128 + swz(kr, kf*32 + (l>>4)*8)];
          n0[mf] = mfmah(bh, qf0[kf], n0[mf]);
          n1[mf] = mfmah(bh, qf1[kf], n1[mf]);
        }
      }
    }
    #pragma unroll
    for (int h=0; h<2; ++h){
      f32x4* f = h ? c1 : c0;
      float& mr = h ? m1r : m0r;
      float& lr = h ? l1r : l0r;
      f32x4* oa = h ? oa1 : oa0;
      unsigned* pk = h ? pk1 : pk0;
      float a0 = fmaxf(fmaxf(f[0][0], f[0][1]), fmaxf(f[0][2], f[0][3]));
      float a1 = fmaxf(fmaxf(f[1][0], f[1][1]), fmaxf(f[1][2], f[1][3]));
      float a2 = fmaxf(fmaxf(f[2][0], f[2][1]), fmaxf(f[2][2], f[2][3]));
      float a3 = fmaxf(fmaxf(f[3][0], f[3][1]), fmaxf(f[3][2], f[3][3]));
      float mx = fmaxf(fmaxf(a0, a1), fmaxf(a2, a3));
      mx = fmaxf(mx, __shfl_xor(mx, 16));
      mx = fmaxf(mx, __shfl_xor(mx, 32));
      if (__any(mx - mr > 11.5f)){   // defer-max (log2 units)
        float mn = fmaxf(mr, mx);
        float al = fexp2(mr - mn);
        mr = mn; lr *= al;
        #pragma unroll
        for (int j=0;j<4;++j){
          float alj = __shfl(al, (l>>4)*4 + j);
          #pragma unroll
          for (int cf=0;cf<8;++cf) oa[cf][j] *= alj;
        }
      }
      float s0 = 0.f, s1 = 0.f, s2 = 0.f, s3 = 0.f;
      #pragma unroll
      for (int mf=0;mf<4;++mf){
        float p0 = fexp2(f[mf][0] - mr);
        float p1 = fexp2(f[mf][1] - mr);
        float p2 = fexp2(f[mf][2] - mr);
        float p3 = fexp2(f[mf][3] - mr);
        pk[2*mf+0] = pk2h(p0, p1);
        pk[2*mf+1] = pk2h(p2, p3);
        s0 += p0; s1 += p1; s2 += p2; s3 += p3;
      }
      lr += (s0 + s1) + (s2 + s3);
    }

    // (4) PV[it]: A from pk regs (kperm order), B from vcur
    __builtin_amdgcn_s_setprio(1);
    {
      int g8 = (l>>4)*8;
      #pragma unroll
      for (int mk=0;mk<2;++mk){
        union { unsigned u[4]; short8 s8; } a0u, a1u;
        #pragma unroll
        for (int q=0;q<4;++q){ a0u.u[q] = pk0[4*mk+q]; a1u.u[q] = pk1[4*mk+q]; }
        #pragma unroll
        for (int cf=0;cf<8;++cf){
          int vr = 16*cf + (l&15);
          short8 bv = *(const short8*)&vcur[vr*64 + swz(vr, mk*32 + g8)];
          oa0[cf] = mfmah(a0u.s8, bv, oa0[cf]);
          oa1[cf] = mfmah(a1u.s8, bv, oa1[cf]);
        }
      }
    }
    __builtin_amdgcn_s_setprio(0);

    // (5) all reads of kcur_n/vcur done before next iter's writes
    __builtin_amdgcn_s_barrier();
  };

  #pragma unroll 1
  for (int i2 = 0; i2 < TPS; i2 += 2){
    iter_body(i2,   0, fa0, fa1, fb0, fb1);
    iter_body(i2+1, 1, fb0, fb1, fa0, fa1);
  }

  // ---- epilogue ----
  #pragma unroll
  for (int h=0; h<2; ++h){
    float mr = h ? m1r : m0r;
    float lr = h ? l1r : l0r;
    f32x4* oa = h ? oa1 : oa0;
    lr += __shfl_xor(lr, 16);
    lr += __shfl_xor(lr, 32);
    float invl = 1.f / lr;
    #pragma unroll
    for (int j=0;j<4;++j){
      float inv = __shfl(invl, (l>>4)*4 + j);
      int n = n0 + h*64 + 16*w + (l>>4)*4 + j;
      #pragma unroll
      for (int cf=0;cf<8;++cf){
        int c = 16*cf + (l&15);
        ypart[(((size_t)s*4 + b)*NSP + n)*ICH + c] = f2h(oa[cf][j]*inv);
      }
    }
    if (l < 16){
      int n = n0 + h*64 + 16*w + l;
      ml[(((size_t)s*4 + b)*NSP + n)*2 + 0] = mr;
      ml[(((size_t)s*4 + b)*NSP + n)*2 + 1] = lr;
    }
  }
}

// ---------------------------------------------------------------------------
// Final conv + fused split-combine (SPL=4)
// ---------------------------------------------------------------------------
template<int SPL>
__global__ __launch_bounds__(256) void final_k(
  const unsigned short* __restrict__ ypart, const float* __restrict__ ml,
  const float* __restrict__ x, const float* __restrict__ Wm,
  const float* __restrict__ bias, const float* __restrict__ gamma,
  const float* __restrict__ beta, const float* __restrict__ mean,
  const float* __restrict__ var, float* __restrict__ out)
{
  const int b = blockIdx.z, ot = blockIdx.y, nt = blockIdx.x;
  const int n0 = nt*64, o0 = ot*64;
  const int t = threadIdx.x, w = t>>6, l = t&63;
  __shared__ unsigned short ys[64][128];
  __shared__ unsigned short w2s[64][128];
  __shared__ float wc[SPL][64];
  __shared__ float sc_s[64], sh_s[64];
  if (t < 64){
    int o = o0 + t;
    float s = gamma[o]*rsqrtf(var[o]+1e-5f);
    sc_s[t]=s; sh_s[t]=beta[o]-mean[o]*s+bias[o]*s;
  } else if (t < 128){
    int r = t - 64, n = n0 + r;
    float mv[SPL], lv[SPL];
    #pragma unroll
    for (int s=0;s<SPL;++s){
      mv[s] = ml[(((size_t)s*4 + b)*NSP + n)*2 + 0];
      lv[s] = ml[(((size_t)s*4 + b)*NSP + n)*2 + 1];
    }
    float M = mv[0];
    #pragma unroll
    for (int s=1;s<SPL;++s) M = fmaxf(M, mv[s]);
    float wsum = 0.f, wv[SPL];
    #pragma unroll
    for (int s=0;s<SPL;++s){ wv[s] = lv[s]*exp2f(mv[s]-M); wsum += wv[s]; }
    float inv = 1.f/wsum;
    #pragma unroll
    for (int s=0;s<SPL;++s) wc[s][r] = wv[s]*inv;
  }
  __syncthreads();
  #pragma unroll
  for (int p=0;p<4;++p){
    int id = p*256 + t, r = id>>4, c8 = (id&15)*8;
    float accv[8] = {0,0,0,0,0,0,0,0};
    #pragma unroll
    for (int s=0;s<SPL;++s){
      short8 v = *(const short8*)(ypart + (((size_t)s*4 + b)*NSP + n0 + r)*ICH + c8);
      float wgt = wc[s][r];
      #pragma unroll
      for (int i=0;i<8;++i) accv[i] += wgt * h2f(((unsigned short*)&v)[i]);
    }
    unsigned short hv[8];
    #pragma unroll
    for (int i=0;i<8;++i) hv[i] = f2h(accv[i]);
    *(short8*)&ys[r][swz(r,c8)] = *(short8*)hv;

    float4 u0 = *(const float4*)(Wm + (size_t)(o0 + r)*ICH + c8);
    float4 u1 = *(const float4*)(Wm + (size_t)(o0 + r)*ICH + c8 + 4);
    unsigned short wh[8] = {f2h(u0.x),f2h(u0.y),f2h(u0.z),f2h(u0.w),
                            f2h(u1.x),f2h(u1.y),f2h(u1.z),f2h(u1.w)};
    *(short8*)&w2s[r][swz(r,c8)] = *(short8*)wh;
  }
  __syncthreads();
  const f32x4 Z = {0.f,0.f,0.f,0.f};
  f32x4 acc[4];
  for (int i=0;i<4;++i) acc[i]=Z;
  #pragma unroll
  for (int kf=0;kf<4;++kf){
    int ko = kf*32 + (l>>4)*8;
    int wr = 16*w + (l&15);
    short8 a = *(const short8*)&w2s[wr][swz(wr,ko)];
    #pragma unroll
    for (int nf=0;nf<4;++nf){
      int yr = 16*nf + (l&15);
      short8 bb = *(const short8*)&ys[yr][swz(yr,ko)];
      acc[nf] = mfmah(a, bb, acc[nf]);
    }
  }
  #pragma unroll
  for (int j=0;j<4;++j){
    int ol = 16*w + (l>>4)*4 + j;
    float s = sc_s[ol], sh = sh_s[ol];
    #pragma unroll
    for (int nf=0;nf<4;++nf){
      int n = n0 + 16*nf + (l&15);
      size_t idx = ((size_t)b*CIN + o0 + ol)*NSP + n;
      out[idx] = acc[nf][j]*s + sh + x[idx];
    }
  }
}

extern "C" void kernel_launch(void* const* d_in, const int* in_sizes, int n_in,
                              void* d_out, int out_size, void* d_ws, size_t ws_size,
                              hipStream_t stream){
  const float* x    = (const float*)d_in[0];
  const float* g_w  = (const float*)d_in[1];
  const float* g_b  = (const float*)d_in[2];
  const float* g_ga = (const float*)d_in[3];
  const float* g_be = (const float*)d_in[4];
  const float* g_me = (const float*)d_in[5];
  const float* g_va = (const float*)d_in[6];
  const float* t_w  = (const float*)d_in[7];
  const float* t_b  = (const float*)d_in[8];
  const float* t_ga = (const float*)d_in[9];
  const float* t_be = (const float*)d_in[10];
  const float* t_me = (const float*)d_in[11];
  const float* t_va = (const float*)d_in[12];
  const float* p_w  = (const float*)d_in[13];
  const float* p_b  = (const float*)d_in[14];
  const float* p_ga = (const float*)d_in[15];
  const float* p_be = (const float*)d_in[16];
  const float* p_me = (const float*)d_in[17];
  const float* p_va = (const float*)d_in[18];
  const float* w_w  = (const float*)d_in[19];
  const float* w_b  = (const float*)d_in[20];
  const float* w_ga = (const float*)d_in[21];
  const float* w_be = (const float*)d_in[22];
  const float* w_me = (const float*)d_in[23];
  const float* w_va = (const float*)d_in[24];

  char* ws = (char*)d_ws;
  const size_t SEG = (size_t)4*NSP*ICH*sizeof(unsigned short);   // 4 MB
  unsigned short* th_t  = (unsigned short*)(ws);
  unsigned short* ph_t  = (unsigned short*)(ws + SEG);
  unsigned short* g_cn  = (unsigned short*)(ws + 2*SEG);
  unsigned short* ypart = (unsigned short*)(ws + 3*SEG);
  float*          mlb   = (float*)(ws + 3*SEG + SPLITS*SEG);

  dim3 blk(256,1,1);
  conv_fused_k<<<dim3(64,2,4), blk, 0, stream>>>(
      x,
      g_w, g_b, g_ga, g_be, g_me, g_va,
      t_w, t_b, t_ga, t_be, t_me, t_va,
      p_w, p_b, p_ga, p_be, p_me, p_va,
      g_cn, th_t, ph_t);
  attn_k<<<dim3(512,1,1), blk, 0, stream>>>(th_t, ph_t, g_cn, ypart, mlb);
  final_k<SPLITS><<<dim3(64,4,4), blk, 0, stream>>>(ypart, mlb, x, w_w, w_b, w_ga, w_be, w_me, w_va, (float*)d_out);
}

// Round 15
// 69.889 us; speedup vs baseline: 1.1306x; 1.1306x over previous
//
#include <hip/hip_runtime.h>
#include <math.h>

typedef __attribute__((ext_vector_type(8))) short short8;
typedef __attribute__((ext_vector_type(8))) _Float16 half8;
typedef __attribute__((ext_vector_type(4))) float f32x4;

#define NSP 4096
#define CIN 256
#define ICH 128
#define SPLITS 4
#define TILES_PER_SPLIT 16
#define LOG2E 1.44269504088896f

__device__ __forceinline__ unsigned short f2h(float x){
  union { _Float16 h; unsigned short u; } v; v.h = (_Float16)x; return v.u;
}
__device__ __forceinline__ float h2f(unsigned short u){
  union { _Float16 h; unsigned short u; } v; v.u = u; return (float)v.h;
}
// pack two f32 -> two f16 in one u32 (v_cvt_pkrtz_f16_f32)
__device__ __forceinline__ unsigned pk2h(float a, float b){
  union { __fp16 __attribute__((ext_vector_type(2))) v; unsigned u; } r;
  r.v = __builtin_amdgcn_cvt_pkrtz(a, b);
  return r.u;
}
// raw 2^x via v_exp_f32 (no OCML denormal fixup)
__device__ __forceinline__ float fexp2(float x){
  float r;
  asm("v_exp_f32 %0, %1" : "=v"(r) : "v"(x));
  return r;
}
// LDS anti-bank-conflict swizzle (element units; 8-chunk preserving)
__device__ __forceinline__ int swz(int row, int e){ return e ^ ((row & 7) << 3); }

__device__ __forceinline__ f32x4 mfmah(short8 a, short8 b, f32x4 c){
  union { short8 s; half8 h; } ua, ub; ua.s = a; ub.s = b;
  return __builtin_amdgcn_mfma_f32_16x16x32_f16(ua.h, ub.h, c, 0, 0, 0);
}

__device__ __forceinline__ void st4h(unsigned short* p, unsigned short a, unsigned short b,
                                     unsigned short c, unsigned short d){
  ushort4 v; v.x=a; v.y=b; v.z=c; v.w=d;
  *(ushort4*)p = v;
}

// async global->LDS, 16B per lane. LDS dest = wave-uniform base + lane*16 (linear).
__device__ __forceinline__ void gload_lds16(const unsigned short* g, unsigned short* l){
  __builtin_amdgcn_global_load_lds(
      (const __attribute__((address_space(1))) unsigned int*)g,
      (__attribute__((address_space(3))) unsigned int*)l, 16, 0, 0);
}

// Stage a 64x128 fp16 tile (row stride 128 elems in global) into LDS flat [64][128]
// with read-side XOR swizzle pre-applied on the SOURCE address (rule 21).
__device__ __forceinline__ void stage_nc(const unsigned short* gbase, unsigned short* lds,
                                         int w, int l){
  #pragma unroll
  for (int i=0;i<4;++i){
    int rl = 16*w + 4*i + (l>>4);
    int eg = ((l&15)*8) ^ ((rl&7)<<3);
    gload_lds16(gbase + (size_t)rl*128 + eg, lds + w*2048 + i*512);
  }
}

// k-order permutation for PV (within each 32-block of m):
// store position p for true m: p = ((m>>4)&1)<<2 | ((m>>2)&3)<<3 | (m&3)
__device__ __forceinline__ int kperm(int q){
  return ((q>>4)&1)*4 + ((q>>2)&3)*8 + (q&3);
}

// ---------------------------------------------------------------------------
// Fused 3-branch conv+BN+ReLU: reads x once, computes g/theta/phi tiles.
// g output is written with kperm-permuted spatial order (PV k-permutation);
// theta output is pre-scaled by log2(e) (softmax runs in exp2 domain).
// ---------------------------------------------------------------------------
__global__ __launch_bounds__(256) void conv_fused_k(
    const float* __restrict__ x,
    const float* __restrict__ w0, const float* __restrict__ b0,
    const float* __restrict__ ga0, const float* __restrict__ be0,
    const float* __restrict__ me0, const float* __restrict__ va0,
    const float* __restrict__ w1, const float* __restrict__ b1,
    const float* __restrict__ ga1, const float* __restrict__ be1,
    const float* __restrict__ me1, const float* __restrict__ va1,
    const float* __restrict__ w2, const float* __restrict__ b2,
    const float* __restrict__ ga2, const float* __restrict__ be2,
    const float* __restrict__ me2, const float* __restrict__ va2,
    unsigned short* __restrict__ outg, unsigned short* __restrict__ outt,
    unsigned short* __restrict__ outp)
{
  const int b = blockIdx.z, nt = blockIdx.x, ot = blockIdx.y;
  const int n0 = nt*64, o0 = ot*64;
  const int t = threadIdx.x, w = t>>6, l = t&63;
  __shared__ unsigned short xs[64][64];       // [n][c] fp16
  __shared__ unsigned short ws[3][64][64];    // [br][o][c] fp16
  __shared__ float sc_s[3][64], sh_s[3][64];
  if (t < 64){
    int o = o0 + t;
    float s0 = ga0[o]*rsqrtf(va0[o]+1e-5f);
    sc_s[0][t]=s0; sh_s[0][t]=be0[o]-me0[o]*s0+b0[o]*s0;
    float s1 = ga1[o]*rsqrtf(va1[o]+1e-5f);
    sc_s[1][t]=s1*LOG2E; sh_s[1][t]=(be1[o]-me1[o]*s1+b1[o]*s1)*LOG2E;
    float s2 = ga2[o]*rsqrtf(va2[o]+1e-5f);
    sc_s[2][t]=s2; sh_s[2][t]=be2[o]-me2[o]*s2+b2[o]*s2;
  }
  const f32x4 Z = {0.f,0.f,0.f,0.f};
  f32x4 acc[3][4];
  #pragma unroll
  for (int br=0;br<3;++br) for (int i=0;i<4;++i) acc[br][i] = Z;
  const float* Wt[3] = {w0, w1, w2};

  for (int kc = 0; kc < CIN; kc += 64){
    __syncthreads();
    #pragma unroll
    for (int p = 0; p < 4; ++p){
      int cw = p*16 + (t>>4);
      int q4 = (t&15)*4;
      float4 xv = *(const float4*)(x + ((size_t)b*CIN + kc + cw)*NSP + n0 + q4);
      float xa[4] = {xv.x, xv.y, xv.z, xv.w};
      #pragma unroll
      for (int i=0;i<4;++i){
        int r = q4 + i;
        xs[r][swz(r, cw)] = f2h(xa[i]);
      }
      #pragma unroll
      for (int br=0;br<3;++br){
        float4 wv = *(const float4*)(Wt[br] + (size_t)(o0 + cw)*CIN + kc + q4);
        int cs = swz(cw, q4);
        st4h(&ws[br][cw][cs], f2h(wv.x), f2h(wv.y), f2h(wv.z), f2h(wv.w));
      }
    }
    __syncthreads();
    #pragma unroll
    for (int kf = 0; kf < 2; ++kf){
      int ko = kf*32 + (l>>4)*8;
      int wr = 16*w + (l&15);
      short8 wf0 = *(const short8*)&ws[0][wr][swz(wr, ko)];
      short8 wf1 = *(const short8*)&ws[1][wr][swz(wr, ko)];
      short8 wf2 = *(const short8*)&ws[2][wr][swz(wr, ko)];
      #pragma unroll
      for (int nf = 0; nf < 4; ++nf){
        int xr = 16*nf + (l&15);
        short8 xf = *(const short8*)&xs[xr][swz(xr, ko)];
        acc[0][nf] = mfmah(wf0, xf, acc[0][nf]);   // orient0 (g)
        acc[1][nf] = mfmah(xf, wf1, acc[1][nf]);   // orient1 (theta)
        acc[2][nf] = mfmah(xf, wf2, acc[2][nf]);   // orient1 (phi)
      }
    }
  }
  // g epilogue (orient0, kperm-permuted column order)
  #pragma unroll
  for (int j=0;j<4;++j){
    int ol = 16*w + (l>>4)*4 + j;
    float s = sc_s[0][ol], sh = sh_s[0][ol];
    #pragma unroll
    for (int nf=0;nf<4;++nf){
      int n = n0 + 16*nf + (l&15);
      int nst = (n & ~31) | kperm(n & 31);
      float v = fmaxf(acc[0][nf][j]*s + sh, 0.f);
      outg[((size_t)b*ICH + o0 + ol)*NSP + nst] = f2h(v);
    }
  }
  // theta/phi epilogue (orient1)
  {
    int ol = 16*w + (l&15);
    float s1 = sc_s[1][ol], sh1 = sh_s[1][ol];
    float s2 = sc_s[2][ol], sh2 = sh_s[2][ol];
    #pragma unroll
    for (int nf=0; nf<4; ++nf)
      #pragma unroll
      for (int j=0;j<4;++j){
        int n = n0 + 16*nf + (l>>4)*4 + j;
        float v1 = fmaxf(acc[1][nf][j]*s1 + sh1, 0.f);
        float v2 = fmaxf(acc[2][nf][j]*s2 + sh2, 0.f);
        outt[((size_t)b*NSP + n)*ICH + o0 + ol] = f2h(v1);
        outp[((size_t)b*NSP + n)*ICH + o0 + ol] = f2h(v2);
      }
  }
}

// ---------------------------------------------------------------------------
// Flash attention (R9 verbatim — the verified best structure).
// Swapped QK^T (P lane-local), kperm register-PV, exp2 softmax (v_exp_f32),
// K/V double-buffered, hoisted staging pointers, one barrier per iteration,
// sum reduction deferred to epilogue.
// ---------------------------------------------------------------------------
__global__ __launch_bounds__(256, 2) void attn_k(
  const unsigned short* __restrict__ thp, const unsigned short* __restrict__ php,
  const unsigned short* __restrict__ gb, unsigned short* __restrict__ ypart,
  float* __restrict__ ml)
{
  // bijective XCD-aware decode: each XCD gets 2 (b,s) combos x 32 qt blocks
  const int bx = blockIdx.x;
  const int xcd = bx & 7, jj = bx >> 3;
  const int combo = xcd*2 + (jj>>5);
  const int qt = jj & 31;
  const int b = combo & 3, s = combo >> 2;
  const int n0 = qt*128;
  const int t = threadIdx.x, w = t>>6, l = t&63;

  __shared__ unsigned short kb[2][64][128];   // K double buffer (32 KB)
  __shared__ unsigned short vb[2][128][64];   // V double buffer (32 KB)

  // ---- stage Q halves through kb[0]/kb[1], pull fragments ----
  stage_nc(thp + ((size_t)b*NSP + n0      )*ICH, &kb[0][0][0], w, l);
  stage_nc(thp + ((size_t)b*NSP + n0 + 64 )*ICH, &kb[1][0][0], w, l);
  __syncthreads();
  short8 qf0[4], qf1[4];
  {
    int qr = 16*w + (l&15);
    #pragma unroll
    for (int kf=0;kf<4;++kf){
      int ko = kf*32 + (l>>4)*8;
      qf0[kf] = *(const short8*)&kb[0][qr][swz(qr, ko)];
      qf1[kf] = *(const short8*)&kb[1][qr][swz(qr, ko)];
    }
  }
  __syncthreads();   // all waves done reading Q before restage

  const f32x4 Z = {0.f,0.f,0.f,0.f};
  f32x4 oa0[8], oa1[8];
  #pragma unroll
  for (int i=0;i<8;++i){ oa0[i]=Z; oa1[i]=Z; }
  float m0r = -1e30f, m1r = -1e30f;
  float l0r = 0.f, l1r = 0.f;
  unsigned pk0[8], pk1[8];

  const int tile0 = s*TILES_PER_SPLIT;

  // ---- hoisted per-lane staging pointers (advance by const stride/iter) ----
  const unsigned short* kp[4];
  const unsigned short* vp[4];
  {
    const unsigned short* kbase = php + ((size_t)b*NSP + tile0*64)*ICH;
    const unsigned short* vbase = gb + (size_t)b*ICH*NSP + tile0*64;
    #pragma unroll
    for (int i=0;i<4;++i){
      int rl = 16*w + 4*i + (l>>4);
      int eg = ((l&15)*8) ^ ((rl&7)<<3);
      kp[i] = kbase + (size_t)rl*128 + eg;
      int cl = 32*w + 8*i + (l>>3);
      int me = ((l&7)*8) ^ ((cl&7)<<3);
      vp[i] = vbase + (size_t)cl*NSP + me;
    }
  }
  // prologue: stage tile0 into buffer 0
  {
    unsigned short* kd = &kb[0][0][0] + w*2048;
    unsigned short* vd = &vb[0][0][0] + w*2048;
    #pragma unroll
    for (int i=0;i<4;++i){
      gload_lds16(kp[i], kd + i*512); kp[i] += 64*ICH;
      gload_lds16(vp[i], vd + i*512); vp[i] += 64;
    }
  }
  __syncthreads();
  int cur = 0;

  for (int it = 0; it < TILES_PER_SPLIT; ++it){
    // (A) prefetch next K+V into other buffers (latency hidden under compute)
    if (it < TILES_PER_SPLIT-1){
      unsigned short* kd = &kb[cur^1][0][0] + w*2048;
      unsigned short* vd = &vb[cur^1][0][0] + w*2048;
      #pragma unroll
      for (int i=0;i<4;++i){
        gload_lds16(kp[i], kd + i*512); kp[i] += 64*ICH;
        gload_lds16(vp[i], vd + i*512); vp[i] += 64;
      }
    }

    // (B) swapped QK^T on kb[cur]: f rows = m (KV), cols = n (Q); K frags shared
    f32x4 f0[4], f1[4];
    #pragma unroll
    for (int i=0;i<4;++i){ f0[i]=Z; f1[i]=Z; }
    __builtin_amdgcn_s_setprio(1);
    #pragma unroll
    for (int mf=0; mf<4; ++mf){
      int kr = 16*mf + (l&15);
      #pragma unroll
      for (int kf=0; kf<4; ++kf){
        short8 bh = *(const short8*)&kb[cur][kr][swz(kr, kf*32 + (l>>4)*8)];
        f0[mf] = mfmah(bh, qf0[kf], f0[mf]);
        f1[mf] = mfmah(bh, qf1[kf], f1[mf]);
      }
    }
    __builtin_amdgcn_s_setprio(0);

    // (C) softmax (exp2 domain, raw v_exp_f32), pack P into registers.
    // Only the MAX needs cross-lane reduction; sum stays per-lane partial.
    #pragma unroll
    for (int h=0; h<2; ++h){
      f32x4* f = h ? f1 : f0;
      float& mr = h ? m1r : m0r;
      float& lr = h ? l1r : l0r;
      f32x4* oa = h ? oa1 : oa0;
      unsigned* pk = h ? pk1 : pk0;
      float a0 = fmaxf(fmaxf(f[0][0], f[0][1]), fmaxf(f[0][2], f[0][3]));
      float a1 = fmaxf(fmaxf(f[1][0], f[1][1]), fmaxf(f[1][2], f[1][3]));
      float a2 = fmaxf(fmaxf(f[2][0], f[2][1]), fmaxf(f[2][2], f[2][3]));
      float a3 = fmaxf(fmaxf(f[3][0], f[3][1]), fmaxf(f[3][2], f[3][3]));
      float mx = fmaxf(fmaxf(a0, a1), fmaxf(a2, a3));
      mx = fmaxf(mx, __shfl_xor(mx, 16));
      mx = fmaxf(mx, __shfl_xor(mx, 32));
      if (__any(mx - mr > 11.5f)){   // defer-max (log2 units; P <= 2^11.5 fits fp16)
        float mn = fmaxf(mr, mx);
        float al = fexp2(mr - mn);   // uniform across the 4 lane-groups
        mr = mn; lr *= al;           // partial sum rescales identically
        #pragma unroll
        for (int j=0;j<4;++j){
          float alj = __shfl(al, (l>>4)*4 + j);
          #pragma unroll
          for (int cf=0;cf<8;++cf) oa[cf][j] *= alj;
        }
      }
      float s0 = 0.f, s1 = 0.f, s2 = 0.f, s3 = 0.f;
      #pragma unroll
      for (int mf=0;mf<4;++mf){
        float p0 = fexp2(f[mf][0] - mr);
        float p1 = fexp2(f[mf][1] - mr);
        float p2 = fexp2(f[mf][2] - mr);
        float p3 = fexp2(f[mf][3] - mr);
        pk[2*mf+0] = pk2h(p0, p1);
        pk[2*mf+1] = pk2h(p2, p3);
        s0 += p0; s1 += p1; s2 += p2; s3 += p3;
      }
      lr += (s0 + s1) + (s2 + s3);
    }

    // (D) PV with permuted k-order: A from pk regs, B from vb[cur] (shared)
    __builtin_amdgcn_s_setprio(1);
    {
      int g8 = (l>>4)*8;
      #pragma unroll
      for (int mk=0;mk<2;++mk){
        union { unsigned u[4]; short8 s8; } a0u, a1u;
        #pragma unroll
        for (int q=0;q<4;++q){ a0u.u[q] = pk0[4*mk+q]; a1u.u[q] = pk1[4*mk+q]; }
        #pragma unroll
        for (int cf=0;cf<8;++cf){
          int vr = 16*cf + (l&15);
          short8 bv = *(const short8*)&vb[cur][vr][swz(vr, mk*32 + g8)];
          oa0[cf] = mfmah(a0u.s8, bv, oa0[cf]);
          oa1[cf] = mfmah(a1u.s8, bv, oa1[cf]);
        }
      }
    }
    __builtin_amdgcn_s_setprio(0);

    __syncthreads();   // drains prefetch (covered by compute) + buffer handoff
    cur ^= 1;
  }

  // ---- epilogue: reduce partial sums across the 4 lane-groups, write out ----
  #pragma unroll
  for (int h=0; h<2; ++h){
    float mr = h ? m1r : m0r;
    float lr = h ? l1r : l0r;
    f32x4* oa = h ? oa1 : oa0;
    lr += __shfl_xor(lr, 16);
    lr += __shfl_xor(lr, 32);
    float invl = 1.f / lr;
    #pragma unroll
    for (int j=0;j<4;++j){
      float inv = __shfl(invl, (l>>4)*4 + j);
      int n = n0 + h*64 + 16*w + (l>>4)*4 + j;
      #pragma unroll
      for (int cf=0;cf<8;++cf){
        int c = 16*cf + (l&15);
        ypart[(((size_t)s*4 + b)*NSP + n)*ICH + c] = f2h(oa[cf][j]*inv);
      }
    }
    if (l < 16){
      int n = n0 + h*64 + 16*w + l;
      ml[(((size_t)s*4 + b)*NSP + n)*2 + 0] = mr;
      ml[(((size_t)s*4 + b)*NSP + n)*2 + 1] = lr;
    }
  }
}

// ---------------------------------------------------------------------------
// Final conv + fused split-combine, 2 o-tiles per block: combine ypart ONCE
// into LDS, then loop over 2 o-tiles staging only W2. Halves ypart re-reads
// and combine VALU vs the per-o-tile variant. Grid (64, 2, 4) = 512 blocks.
// ---------------------------------------------------------------------------
__global__ __launch_bounds__(256) void final_k2(
  const unsigned short* __restrict__ ypart, const float* __restrict__ ml,
  const float* __restrict__ x, const float* __restrict__ Wm,
  const float* __restrict__ bias, const float* __restrict__ gamma,
  const float* __restrict__ beta, const float* __restrict__ mean,
  const float* __restrict__ var, float* __restrict__ out)
{
  const int b = blockIdx.z, oth = blockIdx.y, nt = blockIdx.x;
  const int n0 = nt*64, obase = oth*128;
  const int t = threadIdx.x, w = t>>6, l = t&63;
  __shared__ unsigned short ys[64][128];    // combined y [n][ic]
  __shared__ unsigned short w2s[64][128];   // W2 o-tile [o][ic]
  __shared__ float wc[SPLITS][64];
  __shared__ float sc_s[128], sh_s[128];
  if (t < 128){
    int o = obase + t;
    float s = gamma[o]*rsqrtf(var[o]+1e-5f);
    sc_s[t]=s; sh_s[t]=beta[o]-mean[o]*s+bias[o]*s;
  } else if (t < 192){
    int r = t - 128, n = n0 + r;
    float mv[SPLITS], lv[SPLITS];
    #pragma unroll
    for (int s=0;s<SPLITS;++s){
      mv[s] = ml[(((size_t)s*4 + b)*NSP + n)*2 + 0];
      lv[s] = ml[(((size_t)s*4 + b)*NSP + n)*2 + 1];
    }
    float M = fmaxf(fmaxf(mv[0],mv[1]), fmaxf(mv[2],mv[3]));
    float wsum = 0.f, wv[SPLITS];
    #pragma unroll
    for (int s=0;s<SPLITS;++s){ wv[s] = lv[s]*exp2f(mv[s]-M); wsum += wv[s]; }
    float inv = 1.f/wsum;
    #pragma unroll
    for (int s=0;s<SPLITS;++s) wc[s][r] = wv[s]*inv;
  }
  __syncthreads();
  // combine ypart -> ys (once)
  #pragma unroll
  for (int p=0;p<4;++p){
    int id = p*256 + t, r = id>>4, c8 = (id&15)*8;
    float accv[8] = {0,0,0,0,0,0,0,0};
    #pragma unroll
    for (int s=0;s<SPLITS;++s){
      short8 v = *(const short8*)(ypart + (((size_t)s*4 + b)*NSP + n0 + r)*ICH + c8);
      float wgt = wc[s][r];
      #pragma unroll
      for (int i=0;i<8;++i) accv[i] += wgt * h2f(((unsigned short*)&v)[i]);
    }
    unsigned short hv[8];
    #pragma unroll
    for (int i=0;i<8;++i) hv[i] = f2h(accv[i]);
    *(short8*)&ys[r][swz(r,c8)] = *(short8*)hv;
  }

  const f32x4 Z = {0.f,0.f,0.f,0.f};
  #pragma unroll
  for (int ot2 = 0; ot2 < 2; ++ot2){
    const int o0 = obase + ot2*64;
    // stage W2 o-tile
    #pragma unroll
    for (int p=0;p<4;++p){
      int id = p*256 + t, r = id>>4, c8 = (id&15)*8;
      float4 u0 = *(const float4*)(Wm + (size_t)(o0 + r)*ICH + c8);
      float4 u1 = *(const float4*)(Wm + (size_t)(o0 + r)*ICH + c8 + 4);
      unsigned short wh[8] = {f2h(u0.x),f2h(u0.y),f2h(u0.z),f2h(u0.w),
                              f2h(u1.x),f2h(u1.y),f2h(u1.z),f2h(u1.w)};
      *(short8*)&w2s[r][swz(r,c8)] = *(short8*)wh;
    }
    __syncthreads();   // ys (first pass) + w2s ready
    f32x4 acc[4];
    #pragma unroll
    for (int i=0;i<4;++i) acc[i]=Z;
    #pragma unroll
    for (int kf=0;kf<4;++kf){
      int ko = kf*32 + (l>>4)*8;
      int wr = 16*w + (l&15);
      short8 a = *(const short8*)&w2s[wr][swz(wr,ko)];
      #pragma unroll
      for (int nf=0;nf<4;++nf){
        int yr = 16*nf + (l&15);
        short8 bb = *(const short8*)&ys[yr][swz(yr,ko)];
        acc[nf] = mfmah(a, bb, acc[nf]);
      }
    }
    #pragma unroll
    for (int j=0;j<4;++j){
      int ol = 16*w + (l>>4)*4 + j;
      float s = sc_s[ot2*64 + ol], sh = sh_s[ot2*64 + ol];
      #pragma unroll
      for (int nf=0;nf<4;++nf){
        int n = n0 + 16*nf + (l&15);
        size_t idx = ((size_t)b*CIN + o0 + ol)*NSP + n;
        out[idx] = acc[nf][j]*s + sh + x[idx];
      }
    }
    __syncthreads();   // all reads of w2s done before next o-tile overwrites
  }
}

extern "C" void kernel_launch(void* const* d_in, const int* in_sizes, int n_in,
                              void* d_out, int out_size, void* d_ws, size_t ws_size,
                              hipStream_t stream){
  const float* x    = (const float*)d_in[0];
  const float* g_w  = (const float*)d_in[1];
  const float* g_b  = (const float*)d_in[2];
  const float* g_ga = (const float*)d_in[3];
  const float* g_be = (const float*)d_in[4];
  const float* g_me = (const float*)d_in[5];
  const float* g_va = (const float*)d_in[6];
  const float* t_w  = (const float*)d_in[7];
  const float* t_b  = (const float*)d_in[8];
  const float* t_ga = (const float*)d_in[9];
  const float* t_be = (const float*)d_in[10];
  const float* t_me = (const float*)d_in[11];
  const float* t_va = (const float*)d_in[12];
  const float* p_w  = (const float*)d_in[13];
  const float* p_b  = (const float*)d_in[14];
  const float* p_ga = (const float*)d_in[15];
  const float* p_be = (const float*)d_in[16];
  const float* p_me = (const float*)d_in[17];
  const float* p_va = (const float*)d_in[18];
  const float* w_w  = (const float*)d_in[19];
  const float* w_b  = (const float*)d_in[20];
  const float* w_ga = (const float*)d_in[21];
  const float* w_be = (const float*)d_in[22];
  const float* w_me = (const float*)d_in[23];
  const float* w_va = (const float*)d_in[24];

  char* ws = (char*)d_ws;
  const size_t SEG = (size_t)4*NSP*ICH*sizeof(unsigned short);   // 4 MB
  unsigned short* th_t  = (unsigned short*)(ws);
  unsigned short* ph_t  = (unsigned short*)(ws + SEG);
  unsigned short* g_cn  = (unsigned short*)(ws + 2*SEG);
  unsigned short* ypart = (unsigned short*)(ws + 3*SEG);
  float*          mlb   = (float*)(ws + 3*SEG + SPLITS*SEG);

  dim3 blk(256,1,1);
  conv_fused_k<<<dim3(64,2,4), blk, 0, stream>>>(
      x,
      g_w, g_b, g_ga, g_be, g_me, g_va,
      t_w, t_b, t_ga, t_be, t_me, t_va,
      p_w, p_b, p_ga, p_be, p_me, p_va,
      g_cn, th_t, ph_t);
  attn_k<<<dim3(512,1,1), blk, 0, stream>>>(th_t, ph_t, g_cn, ypart, mlb);
  final_k2<<<dim3(64,2,4), blk, 0, stream>>>(ypart, mlb, x, w_w, w_b, w_ga, w_be, w_me, w_va, (float*)d_out);
}